// Round 2
// baseline (550.082 us; speedup 1.0000x reference)
//
#include <hip/hip_runtime.h>
#include <stdint.h>

typedef unsigned short u16;
typedef __attribute__((ext_vector_type(8))) short bf16x8v;   // 8 bf16 = 4 VGPR (MFMA A/B frag)
typedef __attribute__((ext_vector_type(4))) float f32x4;     // MFMA C/D frag

#define DIM   2048
#define NH    16
#define NKV   8
#define HD    64
#define B_    2
#define S_    2048
#define ROWS  (B_*S_)     // 4096
#define NQKV  4096
#define EPS_   1e-5f
#define SCALE_ 0.125f     // 64^-0.5

__device__ __forceinline__ u16 bfbits(float f) {
  union { float f; unsigned int u; } a; a.f = f;
  unsigned int u = a.u;
  return (u16)((u + 0x7FFFu + ((u >> 16) & 1u)) >> 16);   // RNE f32->bf16
}

__device__ __forceinline__ f32x4 mfma16(bf16x8v a, bf16x8v b, f32x4 c) {
  return __builtin_amdgcn_mfma_f32_16x16x32_bf16(a, b, c, 0, 0, 0);
}

__device__ __forceinline__ void gload_lds16(const void* g, void* l) {
  __builtin_amdgcn_global_load_lds(
      (const __attribute__((address_space(1))) unsigned int*)g,
      (__attribute__((address_space(3))) unsigned int*)l, 16, 0, 0);
}

// ---------------- elementwise cast x -> bf16 ----------------
__global__ void cast_f32_bf16(const float* __restrict__ src, u16* __restrict__ dst, int n4) {
  int i = blockIdx.x * 256 + threadIdx.x;
  if (i >= n4) return;
  float4 v = ((const float4*)src)[i];
  ushort4 o; o.x = bfbits(v.x); o.y = bfbits(v.y); o.z = bfbits(v.z); o.w = bfbits(v.w);
  ((ushort4*)dst)[i] = o;
}

// ---------------- transpose-cast: src fp32 [R][C] -> dst bf16 [C][R] ----------------
__global__ void transpose_cast(const float* __restrict__ src, u16* __restrict__ dst, int R, int C) {
  __shared__ float t[32][33];
  int c0 = blockIdx.x * 32, r0 = blockIdx.y * 32;
  int x = threadIdx.x, y = threadIdx.y;
#pragma unroll
  for (int i = 0; i < 4; ++i) t[y + 8*i][x] = src[(size_t)(r0 + y + 8*i) * C + c0 + x];
  __syncthreads();
#pragma unroll
  for (int i = 0; i < 4; ++i) dst[(size_t)(c0 + y + 8*i) * R + r0 + x] = bfbits(t[x][y + 8*i]);
}

// ---------------- V transpose: qkv fp32 [row][3072 + kv*128 + dv] -> Vt bf16 [b][kv][dv][s] ----------------
__global__ void v_transpose(const float* __restrict__ qkv, u16* __restrict__ Vt) {
  __shared__ float t[32][33];
  int z = blockIdx.z;                // b*8+kv
  int b = z >> 3, kv = z & 7;
  int s0 = blockIdx.x * 32, d0 = blockIdx.y * 32;
  int x = threadIdx.x, y = threadIdx.y;
  const float* src = qkv + (size_t)b * S_ * NQKV + 3072 + kv * 128;
#pragma unroll
  for (int i = 0; i < 4; ++i) t[y + 8*i][x] = src[(size_t)(s0 + y + 8*i) * NQKV + d0 + x];
  __syncthreads();
  u16* dst = Vt + ((size_t)(b * NKV + kv) * 128) * S_;
#pragma unroll
  for (int i = 0; i < 4; ++i) dst[(size_t)(d0 + y + 8*i) * S_ + s0 + x] = bfbits(t[x][y + 8*i]);
}

// ---------------- RoPE (interleaved) + split comps, fp32 in / bf16 out ----------------
// q: hshift=5 (32 rope-heads), coloff=0, D1/D2 have 16 heads.  k: hshift=4, coloff=2048, 8 heads.
__global__ void rope_kernel(const float* __restrict__ qkv, const float* __restrict__ fc,
                            const float* __restrict__ fs, u16* __restrict__ D1, u16* __restrict__ D2,
                            int hshift, int coloff) {
  int p = blockIdx.x * 256 + threadIdx.x;
  int i = p & 31;
  int hh = (p >> 5) & ((1 << hshift) - 1);
  int row = p >> (5 + hshift);
  int s = row & (S_ - 1);
  int b = row >> 11;
  const float* src = qkv + (size_t)row * NQKV + coloff + hh * HD + 2 * i;
  float e = src[0], o = src[1];
  float c = fc[s * 32 + i], sn = fs[s * 32 + i];
  float r0 = e * c - o * sn, r1 = e * sn + o * c;
  u16* dst = (hh & 1) ? D2 : D1;
  int nh = 1 << (hshift - 1);
  size_t offo = (((size_t)b * nh + (hh >> 1)) * S_ + s) * HD + 2 * i;
  unsigned int packed = (unsigned int)bfbits(r0) | ((unsigned int)bfbits(r1) << 16);
  *(unsigned int*)(dst + offo) = packed;
}

// ---------------- lambda scalars ----------------
__global__ void lambda_kernel(const float* lq1, const float* lk1, const float* lq2,
                              const float* lk2, const float* li, float* scal) {
  int t = threadIdx.x;   // 64
  float p1 = lq1[t] * lk1[t];
  float p2 = lq2[t] * lk2[t];
#pragma unroll
  for (int off = 32; off > 0; off >>= 1) { p1 += __shfl_xor(p1, off); p2 += __shfl_xor(p2, off); }
  if (t == 0) {
    scal[0] = __expf(p1) - __expf(p2) + li[0];  // lambda_full
    scal[1] = 1.0f - li[0];                     // output scale
  }
}

// ---------------- GEMM: C fp32 [M][N] = A bf16 [M][K] @ Bt bf16 [N][K]^T ----------------
__global__ __launch_bounds__(256) void gemm_bt(const u16* __restrict__ A, const u16* __restrict__ Bt,
                                               float* __restrict__ C, int M, int N, int K) {
  __shared__ u16 As[128 * 32];
  __shared__ u16 Bs[128 * 32];
  const int tid = threadIdx.x;
  const int wave = tid >> 6, lane = tid & 63;
  const int lr = lane & 15, lk = (lane >> 4) * 8;
  const size_t row0 = (size_t)blockIdx.y * 128, col0 = (size_t)blockIdx.x * 128;
  const int wr = (wave >> 1) * 64, wc = (wave & 1) * 64;
  f32x4 acc[4][4] = {};
  for (int kt = 0; kt < K; kt += 32) {
#pragma unroll
    for (int i = 0; i < 2; ++i) {
      int c = i * 256 + tid;
      int r = c >> 2, c8 = (c & 3) * 8;
      gload_lds16(A  + (row0 + r) * (size_t)K + kt + c8, (char*)As + (i * 256 + wave * 64) * 16);
      gload_lds16(Bt + (col0 + r) * (size_t)K + kt + c8, (char*)Bs + (i * 256 + wave * 64) * 16);
    }
    __syncthreads();
    bf16x8v af[4], bv[4];
#pragma unroll
    for (int m = 0; m < 4; ++m) af[m] = *(const bf16x8v*)(As + (wr + m * 16 + lr) * 32 + lk);
#pragma unroll
    for (int n = 0; n < 4; ++n) bv[n] = *(const bf16x8v*)(Bs + (wc + n * 16 + lr) * 32 + lk);
#pragma unroll
    for (int m = 0; m < 4; ++m)
#pragma unroll
      for (int n = 0; n < 4; ++n) acc[m][n] = mfma16(af[m], bv[n], acc[m][n]);
    __syncthreads();
  }
  const int crow = (lane >> 4) * 4;
#pragma unroll
  for (int m = 0; m < 4; ++m)
#pragma unroll
    for (int n = 0; n < 4; ++n) {
      float* cp = C + (row0 + wr + m * 16 + crow) * (size_t)N + col0 + wc + n * 16 + lr;
#pragma unroll
      for (int j = 0; j < 4; ++j) cp[(size_t)j * N] = acc[m][n][j];
    }
}

// ---------------- fused differential attention ----------------
__device__ __forceinline__ void attn_step(const u16* Ks, const u16* Vts, u16* Pw,
                                          const bf16x8v* qf, float* m, float* l, f32x4* O,
                                          int lr, int lkq, int crow) {
  f32x4 s[4] = {};
#pragma unroll
  for (int kf = 0; kf < 4; ++kf) {
    s[kf] = mfma16(qf[0], *(const bf16x8v*)(Ks + (kf * 16 + lr) * 64 + lkq), s[kf]);
    s[kf] = mfma16(qf[1], *(const bf16x8v*)(Ks + (kf * 16 + lr) * 64 + 32 + lkq), s[kf]);
  }
  float pm[4] = {-1e30f, -1e30f, -1e30f, -1e30f};
#pragma unroll
  for (int kf = 0; kf < 4; ++kf)
#pragma unroll
    for (int j = 0; j < 4; ++j) {
      float sv = s[kf][j] * SCALE_;
      s[kf][j] = sv;
      pm[j] = fmaxf(pm[j], sv);
    }
#pragma unroll
  for (int off = 1; off < 16; off <<= 1)
#pragma unroll
    for (int j = 0; j < 4; ++j) pm[j] = fmaxf(pm[j], __shfl_xor(pm[j], off));
  float al[4], ps[4];
#pragma unroll
  for (int j = 0; j < 4; ++j) {
    float mn = fmaxf(m[j], pm[j]);
    al[j] = __expf(m[j] - mn);
    m[j] = mn;
    ps[j] = 0.f;
  }
#pragma unroll
  for (int kf = 0; kf < 4; ++kf)
#pragma unroll
    for (int j = 0; j < 4; ++j) {
      float p = __expf(s[kf][j] - m[j]);
      s[kf][j] = p;
      ps[j] += p;
    }
#pragma unroll
  for (int off = 1; off < 16; off <<= 1)
#pragma unroll
    for (int j = 0; j < 4; ++j) ps[j] += __shfl_xor(ps[j], off);
#pragma unroll
  for (int j = 0; j < 4; ++j) l[j] = l[j] * al[j] + ps[j];
#pragma unroll
  for (int f = 0; f < 8; ++f)
#pragma unroll
    for (int j = 0; j < 4; ++j) O[f][j] *= al[j];
  // P (C-layout) -> LDS so it can be re-read in A-layout
#pragma unroll
  for (int kf = 0; kf < 4; ++kf)
#pragma unroll
    for (int j = 0; j < 4; ++j)
      Pw[(crow + j) * 64 + kf * 16 + lr] = bfbits(s[kf][j]);
#pragma unroll
  for (int kst = 0; kst < 2; ++kst) {
    bf16x8v pf = *(const bf16x8v*)(Pw + lr * 64 + kst * 32 + lkq);
#pragma unroll
    for (int f = 0; f < 8; ++f) {
      bf16x8v vf = *(const bf16x8v*)(Vts + (f * 16 + lr) * 64 + kst * 32 + lkq);
      O[f] = mfma16(pf, vf, O[f]);
    }
  }
}

__global__ __launch_bounds__(256) void attn_kernel(
    const u16* __restrict__ Q1, const u16* __restrict__ Q2,
    const u16* __restrict__ K1g, const u16* __restrict__ K2g,
    const u16* __restrict__ Vt, const float* __restrict__ scal,
    const float* __restrict__ subw, u16* __restrict__ attnb) {
  __shared__ u16 K1s[64 * 64];
  __shared__ u16 K2s[64 * 64];
  __shared__ u16 Vts[128 * 64];
  __shared__ u16 Ps[4][16 * 64];
  const int qb = blockIdx.x, h = blockIdx.y, b = blockIdx.z;
  const int tid = threadIdx.x;
  const int wave = tid >> 6, lane = tid & 63;
  const int lr = lane & 15, lkq = (lane >> 4) * 8;
  const int crow = (lane >> 4) * 4;
  const int kv = h >> 1;
  const int keybase = (h & 1) * 1024;   // buggy-repeat dedup: head h attends keys [keybase, keybase+1024)

  const int srow = qb * 64 + wave * 16 + lr;
  const u16* q1p = Q1 + (((size_t)b * NH + h) * S_ + srow) * HD + lkq;
  const u16* q2p = Q2 + (((size_t)b * NH + h) * S_ + srow) * HD + lkq;
  bf16x8v q1f[2], q2f[2];
  q1f[0] = *(const bf16x8v*)(q1p);       q1f[1] = *(const bf16x8v*)(q1p + 32);
  q2f[0] = *(const bf16x8v*)(q2p);       q2f[1] = *(const bf16x8v*)(q2p + 32);

  f32x4 O1[8] = {}, O2[8] = {};
  float m1[4], l1[4], m2[4], l2[4];
#pragma unroll
  for (int j = 0; j < 4; ++j) { m1[j] = -1e30f; l1[j] = 0.f; m2[j] = -1e30f; l2[j] = 0.f; }

  const u16* k1b = K1g + ((size_t)b * NKV + kv) * S_ * HD;
  const u16* k2b = K2g + ((size_t)b * NKV + kv) * S_ * HD;
  const u16* vb  = Vt  + ((size_t)b * NKV + kv) * 128 * S_;

  for (int ck = 0; ck < 16; ++ck) {
    const int key0 = keybase + ck * 64;
    // K tiles are [64 keys][64 hd] u16 = 8 chunks of 16B per row: r = c>>3, halfword (c&7)*8.
#pragma unroll
    for (int i = 0; i < 2; ++i) {
      int c = i * 256 + tid;
      gload_lds16(k1b + (size_t)(key0 + (c >> 3)) * HD + (c & 7) * 8, (char*)K1s + (i * 256 + wave * 64) * 16);
      gload_lds16(k2b + (size_t)(key0 + (c >> 3)) * HD + (c & 7) * 8, (char*)K2s + (i * 256 + wave * 64) * 16);
    }
#pragma unroll
    for (int i = 0; i < 4; ++i) {
      int c = i * 256 + tid;
      gload_lds16(vb + (size_t)(c >> 3) * S_ + key0 + (c & 7) * 8, (char*)Vts + (i * 256 + wave * 64) * 16);
    }
    __syncthreads();
    attn_step(K1s, Vts, Ps[wave], q1f, m1, l1, O1, lr, lkq, crow);
    attn_step(K2s, Vts, Ps[wave], q2f, m2, l2, O2, lr, lkq, crow);
    __syncthreads();
  }

  const float lam = scal[0], ofac = scal[1];
  float ssq[4] = {0.f, 0.f, 0.f, 0.f};
#pragma unroll
  for (int f = 0; f < 8; ++f)
#pragma unroll
    for (int j = 0; j < 4; ++j) {
      float cv = O1[f][j] / l1[j] - lam * (O2[f][j] / l2[j]);
      O1[f][j] = cv;
      ssq[j] += cv * cv;
    }
#pragma unroll
  for (int off = 1; off < 16; off <<= 1)
#pragma unroll
    for (int j = 0; j < 4; ++j) ssq[j] += __shfl_xor(ssq[j], off);
  float rs[4];
#pragma unroll
  for (int j = 0; j < 4; ++j) rs[j] = rsqrtf(ssq[j] * (1.f / 128.f) + EPS_) * ofac;
  const size_t rowb = (size_t)b * S_ + qb * 64 + wave * 16 + crow;
#pragma unroll
  for (int f = 0; f < 8; ++f) {
    float sw = subw[f * 16 + lr];
#pragma unroll
    for (int j = 0; j < 4; ++j)
      attnb[(rowb + j) * DIM + h * 128 + f * 16 + lr] = bfbits(O1[f][j] * rs[j] * sw);
  }
}

// ---------------- host ----------------
extern "C" void kernel_launch(void* const* d_in, const int* in_sizes, int n_in,
                              void* d_out, int out_size, void* d_ws, size_t ws_size,
                              hipStream_t stream) {
  const float* x   = (const float*)d_in[0];
  const float* wq  = (const float*)d_in[1];
  const float* wk  = (const float*)d_in[2];
  const float* wv  = (const float*)d_in[3];
  const float* wo  = (const float*)d_in[4];
  const float* lq1 = (const float*)d_in[5];
  const float* lk1 = (const float*)d_in[6];
  const float* lq2 = (const float*)d_in[7];
  const float* lk2 = (const float*)d_in[8];
  const float* li  = (const float*)d_in[9];
  const float* subw= (const float*)d_in[10];
  const float* fc  = (const float*)d_in[11];
  const float* fs  = (const float*)d_in[12];
  float* out = (float*)d_out;

  char* ws = (char*)d_ws;
  size_t off = 0;
  auto alloc = [&](size_t bytes) { char* p = ws + off; off += (bytes + 255) & ~(size_t)255; return p; };
  u16*   xb    = (u16*)alloc((size_t)ROWS * DIM * 2);
  u16*   wqkvT = (u16*)alloc((size_t)NQKV * DIM * 2);
  u16*   woT   = (u16*)alloc((size_t)DIM * DIM * 2);
  float* qkv   = (float*)alloc((size_t)ROWS * NQKV * 4);
  u16*   Q1    = (u16*)alloc((size_t)B_ * NH * S_ * HD * 2);
  u16*   Q2    = (u16*)alloc((size_t)B_ * NH * S_ * HD * 2);
  u16*   K1    = (u16*)alloc((size_t)B_ * NKV * S_ * HD * 2);
  u16*   K2    = (u16*)alloc((size_t)B_ * NKV * S_ * HD * 2);
  u16*   Vt    = (u16*)alloc((size_t)B_ * NKV * 128 * S_ * 2);
  u16*   attnb = (u16*)alloc((size_t)ROWS * DIM * 2);
  float* scal  = (float*)alloc(256);

  cast_f32_bf16<<<ROWS * DIM / 4 / 256, 256, 0, stream>>>(x, xb, ROWS * DIM / 4);
  transpose_cast<<<dim3(64, 64), dim3(32, 8), 0, stream>>>(wq, wqkvT, DIM, DIM);
  transpose_cast<<<dim3(32, 64), dim3(32, 8), 0, stream>>>(wk, wqkvT + (size_t)2048 * DIM, DIM, 1024);
  transpose_cast<<<dim3(32, 64), dim3(32, 8), 0, stream>>>(wv, wqkvT + (size_t)3072 * DIM, DIM, 1024);
  transpose_cast<<<dim3(64, 64), dim3(32, 8), 0, stream>>>(wo, woT, DIM, DIM);

  gemm_bt<<<dim3(NQKV / 128, ROWS / 128), 256, 0, stream>>>(xb, wqkvT, qkv, ROWS, NQKV, DIM);

  rope_kernel<<<ROWS * 32 * 32 / 256, 256, 0, stream>>>(qkv, fc, fs, Q1, Q2, 5, 0);
  rope_kernel<<<ROWS * 16 * 32 / 256, 256, 0, stream>>>(qkv, fc, fs, K1, K2, 4, 2048);
  v_transpose<<<dim3(64, 4, 16), dim3(32, 8), 0, stream>>>(qkv, Vt);
  lambda_kernel<<<1, 64, 0, stream>>>(lq1, lk1, lq2, lk2, li, scal);

  attn_kernel<<<dim3(32, NH, B_), 256, 0, stream>>>(Q1, Q2, K1, K2, Vt, scal, subw, attnb);

  gemm_bt<<<dim3(DIM / 128, ROWS / 128), 256, 0, stream>>>(attnb, woT, out, ROWS, DIM, DIM);
}

// Round 3
// 539.310 us; speedup vs baseline: 1.0200x; 1.0200x over previous
//
#include <hip/hip_runtime.h>
#include <stdint.h>

typedef unsigned short u16;
typedef __attribute__((ext_vector_type(8))) short bf16x8v;   // 8 bf16 = 4 VGPR (MFMA A/B frag)
typedef __attribute__((ext_vector_type(4))) float f32x4;     // MFMA C/D frag

#define DIM   2048
#define NH    16
#define NKV   8
#define HD    64
#define B_    2
#define S_    2048
#define ROWS  (B_*S_)     // 4096
#define NQKV  4096
#define EPS_   1e-5f
#define SCALE_ 0.125f     // 64^-0.5

__device__ __forceinline__ u16 bfbits(float f) {
  union { float f; unsigned int u; } a; a.f = f;
  unsigned int u = a.u;
  return (u16)((u + 0x7FFFu + ((u >> 16) & 1u)) >> 16);   // RNE f32->bf16
}

__device__ __forceinline__ f32x4 mfma16(bf16x8v a, bf16x8v b, f32x4 c) {
  return __builtin_amdgcn_mfma_f32_16x16x32_bf16(a, b, c, 0, 0, 0);
}

__device__ __forceinline__ void gload_lds16(const void* g, void* l) {
  __builtin_amdgcn_global_load_lds(
      (const __attribute__((address_space(1))) unsigned int*)g,
      (__attribute__((address_space(3))) unsigned int*)l, 16, 0, 0);
}

// ---------------- elementwise cast x -> bf16 ----------------
__global__ void cast_f32_bf16(const float* __restrict__ src, u16* __restrict__ dst, int n4) {
  int i = blockIdx.x * 256 + threadIdx.x;
  if (i >= n4) return;
  float4 v = ((const float4*)src)[i];
  ushort4 o; o.x = bfbits(v.x); o.y = bfbits(v.y); o.z = bfbits(v.z); o.w = bfbits(v.w);
  ((ushort4*)dst)[i] = o;
}

// ---------------- transpose-cast: src fp32 [R][C] -> dst bf16 [C][R] ----------------
__global__ void transpose_cast(const float* __restrict__ src, u16* __restrict__ dst, int R, int C) {
  __shared__ float t[32][33];
  int c0 = blockIdx.x * 32, r0 = blockIdx.y * 32;
  int x = threadIdx.x, y = threadIdx.y;
#pragma unroll
  for (int i = 0; i < 4; ++i) t[y + 8*i][x] = src[(size_t)(r0 + y + 8*i) * C + c0 + x];
  __syncthreads();
#pragma unroll
  for (int i = 0; i < 4; ++i) dst[(size_t)(c0 + y + 8*i) * R + r0 + x] = bfbits(t[x][y + 8*i]);
}

// ---------------- V transpose: qkv fp32 [row][3072 + kv*128 + dv] -> Vt bf16 [b][kv][dv][s] ----------------
__global__ void v_transpose(const float* __restrict__ qkv, u16* __restrict__ Vt) {
  __shared__ float t[32][33];
  int z = blockIdx.z;                // b*8+kv
  int b = z >> 3, kv = z & 7;
  int s0 = blockIdx.x * 32, d0 = blockIdx.y * 32;
  int x = threadIdx.x, y = threadIdx.y;
  const float* src = qkv + (size_t)b * S_ * NQKV + 3072 + kv * 128;
#pragma unroll
  for (int i = 0; i < 4; ++i) t[y + 8*i][x] = src[(size_t)(s0 + y + 8*i) * NQKV + d0 + x];
  __syncthreads();
  u16* dst = Vt + ((size_t)(b * NKV + kv) * 128) * S_;
#pragma unroll
  for (int i = 0; i < 4; ++i) dst[(size_t)(d0 + y + 8*i) * S_ + s0 + x] = bfbits(t[x][y + 8*i]);
}

// ---------------- RoPE (interleaved) + split comps, fp32 in / bf16 out ----------------
// q: hshift=5 (32 rope-heads), coloff=0, D1/D2 have 16 heads.  k: hshift=4, coloff=2048, 8 heads.
__global__ void rope_kernel(const float* __restrict__ qkv, const float* __restrict__ fc,
                            const float* __restrict__ fs, u16* __restrict__ D1, u16* __restrict__ D2,
                            int hshift, int coloff) {
  int p = blockIdx.x * 256 + threadIdx.x;
  int i = p & 31;
  int hh = (p >> 5) & ((1 << hshift) - 1);
  int row = p >> (5 + hshift);
  int s = row & (S_ - 1);
  int b = row >> 11;
  const float* src = qkv + (size_t)row * NQKV + coloff + hh * HD + 2 * i;
  float e = src[0], o = src[1];
  float c = fc[s * 32 + i], sn = fs[s * 32 + i];
  float r0 = e * c - o * sn, r1 = e * sn + o * c;
  u16* dst = (hh & 1) ? D2 : D1;
  int nh = 1 << (hshift - 1);
  size_t offo = (((size_t)b * nh + (hh >> 1)) * S_ + s) * HD + 2 * i;
  unsigned int packed = (unsigned int)bfbits(r0) | ((unsigned int)bfbits(r1) << 16);
  *(unsigned int*)(dst + offo) = packed;
}

// ---------------- lambda scalars ----------------
__global__ void lambda_kernel(const float* lq1, const float* lk1, const float* lq2,
                              const float* lk2, const float* li, float* scal) {
  int t = threadIdx.x;   // 64
  float p1 = lq1[t] * lk1[t];
  float p2 = lq2[t] * lk2[t];
#pragma unroll
  for (int off = 32; off > 0; off >>= 1) { p1 += __shfl_xor(p1, off); p2 += __shfl_xor(p2, off); }
  if (t == 0) {
    scal[0] = __expf(p1) - __expf(p2) + li[0];  // lambda_full
    scal[1] = 1.0f - li[0];                     // output scale
  }
}

// ---------------- GEMM: C fp32 [M][N] = A bf16 [M][K] @ Bt bf16 [N][K]^T ----------------
__global__ __launch_bounds__(256) void gemm_bt(const u16* __restrict__ A, const u16* __restrict__ Bt,
                                               float* __restrict__ C, int M, int N, int K) {
  __shared__ u16 As[128 * 32];
  __shared__ u16 Bs[128 * 32];
  const int tid = threadIdx.x;
  const int wave = tid >> 6, lane = tid & 63;
  const int lr = lane & 15, lk = (lane >> 4) * 8;
  const size_t row0 = (size_t)blockIdx.y * 128, col0 = (size_t)blockIdx.x * 128;
  const int wr = (wave >> 1) * 64, wc = (wave & 1) * 64;
  f32x4 acc[4][4] = {};
  for (int kt = 0; kt < K; kt += 32) {
#pragma unroll
    for (int i = 0; i < 2; ++i) {
      int c = i * 256 + tid;
      int r = c >> 2, c8 = (c & 3) * 8;
      gload_lds16(A  + (row0 + r) * (size_t)K + kt + c8, (char*)As + (i * 256 + wave * 64) * 16);
      gload_lds16(Bt + (col0 + r) * (size_t)K + kt + c8, (char*)Bs + (i * 256 + wave * 64) * 16);
    }
    __syncthreads();
    bf16x8v af[4], bv[4];
#pragma unroll
    for (int m = 0; m < 4; ++m) af[m] = *(const bf16x8v*)(As + (wr + m * 16 + lr) * 32 + lk);
#pragma unroll
    for (int n = 0; n < 4; ++n) bv[n] = *(const bf16x8v*)(Bs + (wc + n * 16 + lr) * 32 + lk);
#pragma unroll
    for (int m = 0; m < 4; ++m)
#pragma unroll
      for (int n = 0; n < 4; ++n) acc[m][n] = mfma16(af[m], bv[n], acc[m][n]);
    __syncthreads();
  }
  const int crow = (lane >> 4) * 4;
#pragma unroll
  for (int m = 0; m < 4; ++m)
#pragma unroll
    for (int n = 0; n < 4; ++n) {
      float* cp = C + (row0 + wr + m * 16 + crow) * (size_t)N + col0 + wc + n * 16 + lr;
#pragma unroll
      for (int j = 0; j < 4; ++j) cp[(size_t)j * N] = acc[m][n][j];
    }
}

// ---------------- fused differential attention ----------------
// All LDS tiles are [rows][8 chunks of 16B] with XOR swizzle: physical chunk
// c_phys at row r holds logical chunk c_phys ^ (r&7). Staged via per-lane
// pre-swizzled global source (rule #21); every ds_read applies c ^ (r&7).
__device__ __forceinline__ void attn_step(const u16* Ks, const u16* Vts, u16* Pw,
                                          const bf16x8v* qf, float* m, float* l, f32x4* O,
                                          int lane) {
  const int lr = lane & 15, cq = lane >> 4, crow = cq * 4;
  f32x4 s[4] = {};
#pragma unroll
  for (int kf = 0; kf < 4; ++kf) {
    const int row = kf * 16 + lr, sw = row & 7;
    s[kf] = mfma16(qf[0], *(const bf16x8v*)(Ks + row * 64 + ((cq ^ sw) * 8)), s[kf]);
    s[kf] = mfma16(qf[1], *(const bf16x8v*)(Ks + row * 64 + (((cq + 4) ^ sw) * 8)), s[kf]);
  }
  float pm[4] = {-1e30f, -1e30f, -1e30f, -1e30f};
#pragma unroll
  for (int kf = 0; kf < 4; ++kf)
#pragma unroll
    for (int j = 0; j < 4; ++j) {
      float sv = s[kf][j] * SCALE_;
      s[kf][j] = sv;
      pm[j] = fmaxf(pm[j], sv);
    }
#pragma unroll
  for (int off = 1; off < 16; off <<= 1)
#pragma unroll
    for (int j = 0; j < 4; ++j) pm[j] = fmaxf(pm[j], __shfl_xor(pm[j], off));
  float al[4], ps[4];
#pragma unroll
  for (int j = 0; j < 4; ++j) {
    float mn = fmaxf(m[j], pm[j]);
    al[j] = __expf(m[j] - mn);
    m[j] = mn;
    ps[j] = 0.f;
  }
#pragma unroll
  for (int kf = 0; kf < 4; ++kf)
#pragma unroll
    for (int j = 0; j < 4; ++j) {
      float p = __expf(s[kf][j] - m[j]);
      s[kf][j] = p;
      ps[j] += p;
    }
#pragma unroll
  for (int off = 1; off < 16; off <<= 1)
#pragma unroll
    for (int j = 0; j < 4; ++j) ps[j] += __shfl_xor(ps[j], off);
#pragma unroll
  for (int j = 0; j < 4; ++j) l[j] = l[j] * al[j] + ps[j];
#pragma unroll
  for (int f = 0; f < 8; ++f)
#pragma unroll
    for (int j = 0; j < 4; ++j) O[f][j] *= al[j];
  // P (C-layout) -> LDS (swizzled) so it can be re-read in A-layout
#pragma unroll
  for (int kf = 0; kf < 4; ++kf) {
    const int ch = kf * 2 + (lr >> 3), cl = lr & 7;   // col = kf*16+lr -> chunk, within-chunk
#pragma unroll
    for (int j = 0; j < 4; ++j) {
      const int row = crow + j;
      Pw[row * 64 + ((ch ^ (row & 7)) * 8) + cl] = bfbits(s[kf][j]);
    }
  }
#pragma unroll
  for (int kst = 0; kst < 2; ++kst) {
    bf16x8v pf = *(const bf16x8v*)(Pw + lr * 64 + (((kst * 4 + cq) ^ (lr & 7)) * 8));
#pragma unroll
    for (int f = 0; f < 8; ++f) {
      const int row = f * 16 + lr;
      bf16x8v vf = *(const bf16x8v*)(Vts + row * 64 + (((kst * 4 + cq) ^ (row & 7)) * 8));
      O[f] = mfma16(pf, vf, O[f]);
    }
  }
}

__global__ __launch_bounds__(256) void attn_kernel(
    const u16* __restrict__ Q1, const u16* __restrict__ Q2,
    const u16* __restrict__ K1g, const u16* __restrict__ K2g,
    const u16* __restrict__ Vt, const float* __restrict__ scal,
    const float* __restrict__ subw, u16* __restrict__ attnb) {
  __shared__ u16 K1s[64 * 64];
  __shared__ u16 K2s[64 * 64];
  __shared__ u16 Vts[128 * 64];
  __shared__ u16 Ps[4][16 * 64];
  const int qb = blockIdx.x, h = blockIdx.y, b = blockIdx.z;
  const int tid = threadIdx.x;
  const int wave = tid >> 6, lane = tid & 63;
  const int lr = lane & 15, lkq = (lane >> 4) * 8;
  const int crow = (lane >> 4) * 4;
  const int kv = h >> 1;
  const int keybase = (h & 1) * 1024;   // buggy-repeat dedup: head h attends keys [keybase, keybase+1024)

  const int srow = qb * 64 + wave * 16 + lr;
  const u16* q1p = Q1 + (((size_t)b * NH + h) * S_ + srow) * HD + lkq;
  const u16* q2p = Q2 + (((size_t)b * NH + h) * S_ + srow) * HD + lkq;
  bf16x8v q1f[2], q2f[2];
  q1f[0] = *(const bf16x8v*)(q1p);       q1f[1] = *(const bf16x8v*)(q1p + 32);
  q2f[0] = *(const bf16x8v*)(q2p);       q2f[1] = *(const bf16x8v*)(q2p + 32);

  f32x4 O1[8] = {}, O2[8] = {};
  float m1[4], l1[4], m2[4], l2[4];
#pragma unroll
  for (int j = 0; j < 4; ++j) { m1[j] = -1e30f; l1[j] = 0.f; m2[j] = -1e30f; l2[j] = 0.f; }

  const u16* k1b = K1g + ((size_t)b * NKV + kv) * S_ * HD;
  const u16* k2b = K2g + ((size_t)b * NKV + kv) * S_ * HD;
  const u16* vb  = Vt  + ((size_t)b * NKV + kv) * 128 * S_;

  for (int ck = 0; ck < 16; ++ck) {
    const int key0 = keybase + ck * 64;
    // K tiles: [64 keys][8 chunks]. Linear LDS dest; source chunk = phys ^ (row&7).
#pragma unroll
    for (int i = 0; i < 2; ++i) {
      int n = i * 256 + tid;
      int r = n >> 3, cl = (n & 7) ^ (r & 7);
      gload_lds16(k1b + (size_t)(key0 + r) * HD + cl * 8, (char*)K1s + (i * 256 + wave * 64) * 16);
      gload_lds16(k2b + (size_t)(key0 + r) * HD + cl * 8, (char*)K2s + (i * 256 + wave * 64) * 16);
    }
#pragma unroll
    for (int i = 0; i < 4; ++i) {
      int n = i * 256 + tid;
      int r = n >> 3, cl = (n & 7) ^ (r & 7);
      gload_lds16(vb + (size_t)r * S_ + key0 + cl * 8, (char*)Vts + (i * 256 + wave * 64) * 16);
    }
    __syncthreads();
    attn_step(K1s, Vts, Ps[wave], q1f, m1, l1, O1, lane);
    attn_step(K2s, Vts, Ps[wave], q2f, m2, l2, O2, lane);
    __syncthreads();
  }

  const float lam = scal[0], ofac = scal[1];
  float ssq[4] = {0.f, 0.f, 0.f, 0.f};
#pragma unroll
  for (int f = 0; f < 8; ++f)
#pragma unroll
    for (int j = 0; j < 4; ++j) {
      float cv = O1[f][j] / l1[j] - lam * (O2[f][j] / l2[j]);
      O1[f][j] = cv;
      ssq[j] += cv * cv;
    }
#pragma unroll
  for (int off = 1; off < 16; off <<= 1)
#pragma unroll
    for (int j = 0; j < 4; ++j) ssq[j] += __shfl_xor(ssq[j], off);
  float rs[4];
#pragma unroll
  for (int j = 0; j < 4; ++j) rs[j] = rsqrtf(ssq[j] * (1.f / 128.f) + EPS_) * ofac;
  const size_t rowb = (size_t)b * S_ + qb * 64 + wave * 16 + crow;
#pragma unroll
  for (int f = 0; f < 8; ++f) {
    float sw = subw[f * 16 + lr];
#pragma unroll
    for (int j = 0; j < 4; ++j)
      attnb[(rowb + j) * DIM + h * 128 + f * 16 + lr] = bfbits(O1[f][j] * rs[j] * sw);
  }
}

// ---------------- host ----------------
extern "C" void kernel_launch(void* const* d_in, const int* in_sizes, int n_in,
                              void* d_out, int out_size, void* d_ws, size_t ws_size,
                              hipStream_t stream) {
  const float* x   = (const float*)d_in[0];
  const float* wq  = (const float*)d_in[1];
  const float* wk  = (const float*)d_in[2];
  const float* wv  = (const float*)d_in[3];
  const float* wo  = (const float*)d_in[4];
  const float* lq1 = (const float*)d_in[5];
  const float* lk1 = (const float*)d_in[6];
  const float* lq2 = (const float*)d_in[7];
  const float* lk2 = (const float*)d_in[8];
  const float* li  = (const float*)d_in[9];
  const float* subw= (const float*)d_in[10];
  const float* fc  = (const float*)d_in[11];
  const float* fs  = (const float*)d_in[12];
  float* out = (float*)d_out;

  char* ws = (char*)d_ws;
  size_t off = 0;
  auto alloc = [&](size_t bytes) { char* p = ws + off; off += (bytes + 255) & ~(size_t)255; return p; };
  u16*   xb    = (u16*)alloc((size_t)ROWS * DIM * 2);
  u16*   wqkvT = (u16*)alloc((size_t)NQKV * DIM * 2);
  u16*   woT   = (u16*)alloc((size_t)DIM * DIM * 2);
  float* qkv   = (float*)alloc((size_t)ROWS * NQKV * 4);
  u16*   Q1    = (u16*)alloc((size_t)B_ * NH * S_ * HD * 2);
  u16*   Q2    = (u16*)alloc((size_t)B_ * NH * S_ * HD * 2);
  u16*   K1    = (u16*)alloc((size_t)B_ * NKV * S_ * HD * 2);
  u16*   K2    = (u16*)alloc((size_t)B_ * NKV * S_ * HD * 2);
  u16*   Vt    = (u16*)alloc((size_t)B_ * NKV * 128 * S_ * 2);
  u16*   attnb = (u16*)alloc((size_t)ROWS * DIM * 2);
  float* scal  = (float*)alloc(256);

  cast_f32_bf16<<<ROWS * DIM / 4 / 256, 256, 0, stream>>>(x, xb, ROWS * DIM / 4);
  transpose_cast<<<dim3(64, 64), dim3(32, 8), 0, stream>>>(wq, wqkvT, DIM, DIM);
  transpose_cast<<<dim3(32, 64), dim3(32, 8), 0, stream>>>(wk, wqkvT + (size_t)2048 * DIM, DIM, 1024);
  transpose_cast<<<dim3(32, 64), dim3(32, 8), 0, stream>>>(wv, wqkvT + (size_t)3072 * DIM, DIM, 1024);
  transpose_cast<<<dim3(64, 64), dim3(32, 8), 0, stream>>>(wo, woT, DIM, DIM);

  gemm_bt<<<dim3(NQKV / 128, ROWS / 128), 256, 0, stream>>>(xb, wqkvT, qkv, ROWS, NQKV, DIM);

  rope_kernel<<<ROWS * 32 * 32 / 256, 256, 0, stream>>>(qkv, fc, fs, Q1, Q2, 5, 0);
  rope_kernel<<<ROWS * 16 * 32 / 256, 256, 0, stream>>>(qkv, fc, fs, K1, K2, 4, 2048);
  v_transpose<<<dim3(64, 4, 16), dim3(32, 8), 0, stream>>>(qkv, Vt);
  lambda_kernel<<<1, 64, 0, stream>>>(lq1, lk1, lq2, lk2, li, scal);

  attn_kernel<<<dim3(32, NH, B_), 256, 0, stream>>>(Q1, Q2, K1, K2, Vt, scal, subw, attnb);

  gemm_bt<<<dim3(DIM / 128, ROWS / 128), 256, 0, stream>>>(attnb, woT, out, ROWS, DIM, DIM);
}